// Round 1
// baseline (3374.138 us; speedup 1.0000x reference)
//
#include <hip/hip_runtime.h>
#include <math.h>

// Problem constants
#define NN   16
#define C_   128
#define HH   128
#define WW   128
#define CHID 32

// Conv tiling
#define TH   8
#define TW   32
#define NCO  8
#define CICH 8
#define TILES_X (WW / TW)            // 4
#define TILES_Y (HH / TH)            // 16
#define NTILES  (TILES_X * TILES_Y)  // 64

// Direct 3x3 conv, padding=1. Each block: one (n, 8-c_out group, 8x32 spatial tile).
// Input tile staged in LDS per 8-channel chunk; weights read via wave-uniform
// addresses (scalar loads). Optionally fuses PReLU; optionally emits per-block
// partial sums (for the global average pool) deterministically.
template<bool PRELU, bool PARTIAL>
__global__ __launch_bounds__(256) void conv3x3_k(
    const float* __restrict__ in, const float* __restrict__ w,
    const float* __restrict__ bias, const float* __restrict__ prelu_a,
    float* __restrict__ out, float* __restrict__ partial)
{
    __shared__ float s_in[CICH][TH + 2][TW + 2];   // 8*10*34*4 = 10880 B
    __shared__ float s_red[4][NCO];

    const int tid    = threadIdx.x;
    const int tile   = blockIdx.x;           // 0..63
    const int cog    = blockIdx.y;           // 0..15
    const int n      = blockIdx.z;           // 0..15
    const int tile_y = tile / TILES_X;
    const int tile_x = tile % TILES_X;
    const int y0 = tile_y * TH, x0 = tile_x * TW;
    const int ty = tid >> 5, tx = tid & 31;  // 8 x 32 threads
    const int co_base = cog * NCO;

    float acc[NCO];
#pragma unroll
    for (int i = 0; i < NCO; ++i) acc[i] = 0.f;

    const float* wbase  = w + (size_t)co_base * (C_ * 9);
    const float* inbase = in + (size_t)n * C_ * HH * WW;

    for (int cib = 0; cib < C_ / CICH; ++cib) {
        __syncthreads();
        const int ci0 = cib * CICH;
        // stage 8 channels x 10 x 34 patch (zero-padded at image boundary)
        for (int i = tid; i < CICH * (TH + 2) * (TW + 2); i += 256) {
            int ci = i / ((TH + 2) * (TW + 2));
            int r  = i % ((TH + 2) * (TW + 2));
            int yy = r / (TW + 2), xx = r % (TW + 2);
            int gy = y0 + yy - 1, gx = x0 + xx - 1;
            float v = 0.f;
            if (gy >= 0 && gy < HH && gx >= 0 && gx < WW)
                v = inbase[(size_t)(ci0 + ci) * HH * WW + gy * WW + gx];
            s_in[ci][yy][xx] = v;
        }
        __syncthreads();

        for (int ci = 0; ci < CICH; ++ci) {
#pragma unroll
            for (int ky = 0; ky < 3; ++ky) {
#pragma unroll
                for (int kx = 0; kx < 3; ++kx) {
                    float iv = s_in[ci][ty + ky][tx + kx];
#pragma unroll
                    for (int co = 0; co < NCO; ++co) {
                        // wave-uniform address -> scalar load, FMA takes SGPR operand
                        float wv = wbase[(size_t)co * (C_ * 9) + (ci0 + ci) * 9 + ky * 3 + kx];
                        acc[co] = fmaf(iv, wv, acc[co]);
                    }
                }
            }
        }
    }

    const int y = y0 + ty, x = x0 + tx;
    const float a1 = PRELU ? *prelu_a : 0.f;
    float vout[NCO];
#pragma unroll
    for (int co = 0; co < NCO; ++co) {
        float v = acc[co] + bias[co_base + co];
        if (PRELU) v = (v >= 0.f) ? v : a1 * v;
        vout[co] = v;
        out[((size_t)(n * C_ + co_base + co) * HH + y) * WW + x] = v;
    }

    if (PARTIAL) {
        const int wave = tid >> 6, lane = tid & 63;
#pragma unroll
        for (int co = 0; co < NCO; ++co) {
            float s = vout[co];
#pragma unroll
            for (int off = 32; off >= 1; off >>= 1) s += __shfl_down(s, off);
            if (lane == 0) s_red[wave][co] = s;
        }
        __syncthreads();
        if (tid < NCO) {
            float s = s_red[0][tid] + s_red[1][tid] + s_red[2][tid] + s_red[3][tid];
            partial[(size_t)(n * C_ + co_base + tid) * NTILES + tile] = s;
        }
    }
}

// One block per sample: reduce partial sums -> x1[c], expert MLP, sigmoid gate.
__global__ __launch_bounds__(C_) void adapter_k(
    const float* __restrict__ partial, const int* __restrict__ intensity,
    const float* __restrict__ aW1, const float* __restrict__ ab1,
    const float* __restrict__ aW2, const float* __restrict__ ab2,
    float* __restrict__ sig)
{
    __shared__ float sx[C_];
    __shared__ float sa[CHID];
    const int n = blockIdx.x, c = threadIdx.x;

    float s = 0.f;
    for (int t = 0; t < NTILES; ++t)
        s += partial[(size_t)(n * C_ + c) * NTILES + t];
    sx[c] = s * (1.f / (float)(HH * WW));
    __syncthreads();

    const int idx = intensity[n] - 1;
    if (c < CHID) {
        float a = ab1[idx * CHID + c];
        const float* wrow = aW1 + (size_t)(idx * CHID + c) * C_;
        for (int k = 0; k < C_; ++k) a = fmaf(wrow[k], sx[k], a);
        sa[c] = fmaxf(a, 0.f);
    }
    __syncthreads();

    float g = ab2[idx * C_ + c];
    const float* w2row = aW2 + (size_t)(idx * C_ + c) * CHID;
#pragma unroll
    for (int k = 0; k < CHID; ++k) g = fmaf(w2row[k], sa[k], g);
    sig[n * C_ + c] = 1.f / (1.f + expf(-g));
}

// out = prelu(h * sig[n,c] + x, p2), in-place on d_out (h lives there).
__global__ __launch_bounds__(256) void epilogue_k(
    const float* __restrict__ x, const float* __restrict__ sig,
    const float* __restrict__ prelu_a, float* __restrict__ out, int total4)
{
    const float a = *prelu_a;
    const int stride = gridDim.x * blockDim.x;
    for (int i = blockIdx.x * blockDim.x + threadIdx.x; i < total4; i += stride) {
        const int nc = (i * 4) >> 14;          // 16384 elems per (n,c); 4-aligned
        const float s = sig[nc];
        float4 h4 = ((const float4*)out)[i];
        float4 x4 = ((const float4*)x)[i];
        float4 v;
        v.x = h4.x * s + x4.x;  v.x = (v.x >= 0.f) ? v.x : a * v.x;
        v.y = h4.y * s + x4.y;  v.y = (v.y >= 0.f) ? v.y : a * v.y;
        v.z = h4.z * s + x4.z;  v.z = (v.z >= 0.f) ? v.z : a * v.z;
        v.w = h4.w * s + x4.w;  v.w = (v.w >= 0.f) ? v.w : a * v.w;
        ((float4*)out)[i] = v;
    }
}

extern "C" void kernel_launch(void* const* d_in, const int* in_sizes, int n_in,
                              void* d_out, int out_size, void* d_ws, size_t ws_size,
                              hipStream_t stream)
{
    const float* x         = (const float*)d_in[0];
    const int*   intensity = (const int*)  d_in[1];
    const float* w1        = (const float*)d_in[2];
    const float* b1        = (const float*)d_in[3];
    const float* p1        = (const float*)d_in[4];
    const float* w2        = (const float*)d_in[5];
    const float* b2        = (const float*)d_in[6];
    const float* aW1       = (const float*)d_in[7];
    const float* ab1       = (const float*)d_in[8];
    const float* aW2       = (const float*)d_in[9];
    const float* ab2       = (const float*)d_in[10];
    const float* p2        = (const float*)d_in[11];
    float* out = (float*)d_out;

    // workspace layout: h1 (conv1 output) | partial sums | sig
    float* h1      = (float*)d_ws;
    float* partial = (float*)((char*)d_ws + (size_t)NN * C_ * HH * WW * sizeof(float));
    float* sig     = partial + (size_t)NN * C_ * NTILES;

    dim3 grid(NTILES, C_ / NCO, NN), block(256);
    // conv1 + PReLU -> h1 (ws)
    conv3x3_k<true, false><<<grid, block, 0, stream>>>(x, w1, b1, p1, h1, nullptr);
    // conv2 -> h (stored in d_out), + per-block partial sums for avg-pool
    conv3x3_k<false, true><<<grid, block, 0, stream>>>(h1, w2, b2, nullptr, out, partial);
    // avg-pool reduce + expert MLP + sigmoid
    adapter_k<<<dim3(NN), dim3(C_), 0, stream>>>(partial, intensity, aW1, ab1, aW2, ab2, sig);
    // gated residual + PReLU, in-place on d_out
    const int total4 = NN * C_ * HH * WW / 4;
    epilogue_k<<<dim3(2048), dim3(256), 0, stream>>>(x, sig, p2, out, total4);
}

// Round 2
// 297.186 us; speedup vs baseline: 11.3536x; 11.3536x over previous
//
#include <hip/hip_runtime.h>
#include <hip/hip_bf16.h>
#include <math.h>

#define NN   16
#define C_   128
#define HH   128
#define WW   128
#define CHID 32
#define NTILES 64   // one tile per output y-pair

typedef short bf16x8 __attribute__((ext_vector_type(8)));
typedef float f32x4  __attribute__((ext_vector_type(4)));

__device__ inline void glds16(const void* g, void* l) {
    __builtin_amdgcn_global_load_lds(
        (const __attribute__((address_space(1))) unsigned int*)g,
        (__attribute__((address_space(3))) unsigned int*)l, 16, 0, 0);
}

__device__ inline unsigned short f2bf(float f) {
    __hip_bfloat16 h = __float2bfloat16(f);
    return *reinterpret_cast<unsigned short*>(&h);
}

// ---------------------------------------------------------------------------
// Pack conv weights into MFMA-A fragment-linear layout (bf16):
// wl[conv][kk 9][ck 4][cot 8][lane 64][8] ; value = W[co][ci][ky][kx]
// with co = cot*16 + (l&15), ci = ck*32 + (l>>4)*8 + j, kk = ky*3+kx.
__global__ __launch_bounds__(64) void pack_w_k(
    const float* __restrict__ w1, const float* __restrict__ w2,
    unsigned short* __restrict__ wl)
{
    const int b = blockIdx.x;                 // conv*288 + kk*32 + ck*8 + cot
    const int conv = b / 288, rem = b % 288;
    const int kk = rem / 32, ck = (rem % 32) / 8, cot = rem % 8;
    const int l = threadIdx.x;
    const int co  = cot * 16 + (l & 15);
    const int ci0 = ck * 32 + (l >> 4) * 8;
    const float* W = conv ? w2 : w1;
    union { unsigned short u[8]; uint4 v; } pk;
#pragma unroll
    for (int j = 0; j < 8; ++j)
        pk.u[j] = f2bf(W[(size_t)(co * C_ + ci0 + j) * 9 + kk]);
    unsigned short* dst = wl + (size_t)conv * 147456 +
        ((((size_t)kk * 4 + ck) * 8 + cot) * 64 + l) * 8;
    *reinterpret_cast<uint4*>(dst) = pk.v;
}

// ---------------------------------------------------------------------------
// fp32 NCHW -> bf16 chunked-NHWC: xb[n][y][ck4][x128][ci32]
__global__ __launch_bounds__(256) void to_cnhwc_k(
    const float* __restrict__ x, unsigned short* __restrict__ xb)
{
    __shared__ unsigned short s_t[128][136];   // [x][ci], row 272B (16B-aligned)
    const int y = blockIdx.x, n = blockIdx.y, t = threadIdx.x;

#pragma unroll
    for (int p = 0; p < 16; ++p) {
        int fi = p * 256 + t;                  // float4 index over [ci][x/4]
        int ci = fi >> 5, x0 = (fi & 31) * 4;
        float4 v = *reinterpret_cast<const float4*>(
            x + (((size_t)(n * C_ + ci) * HH) + y) * WW + x0);
        s_t[x0 + 0][ci] = f2bf(v.x);
        s_t[x0 + 1][ci] = f2bf(v.y);
        s_t[x0 + 2][ci] = f2bf(v.z);
        s_t[x0 + 3][ci] = f2bf(v.w);
    }
    __syncthreads();
    unsigned short* dstbase = xb + ((size_t)(n * HH + y)) * 16384;
#pragma unroll
    for (int p = 0; p < 8; ++p) {
        int o = p * 256 + t;                   // 16B unit: 2048 total
        int ck = o >> 9, u = o & 511;
        int xc = u >> 2, ci0 = (u & 3) * 8;
        uint4 v = *reinterpret_cast<const uint4*>(&s_t[xc][ck * 32 + ci0]);
        *reinterpret_cast<uint4*>(dstbase + (size_t)ck * 4096 + xc * 32 + ci0) = v;
    }
}

// ---------------------------------------------------------------------------
// Implicit-GEMM 3x3 conv. Block: 128 c_out x (2 rows x 128 x) at (n, yp).
// 8 waves: w -> wco = w>>2, wy = (w>>1)&1, wxh = w&1 ; wave tile 64co x 64x.
// CONV==1: out bf16 chunked-NHWC + PReLU. CONV==2: out fp32 NCHW + partials.
template<int CONV>
__global__ __launch_bounds__(512) void conv_mfma_k(
    const unsigned short* __restrict__ inb,   // bf16 chunked-NHWC
    const unsigned short* __restrict__ wl,    // this conv's packed frags
    const float* __restrict__ bias,
    const float* __restrict__ prelu_a,
    unsigned short* __restrict__ outb,        // CONV==1
    float* __restrict__ outf,                 // CONV==2
    float* __restrict__ partial)              // CONV==2
{
    __shared__ unsigned short sB[4][132][32]; // [yrow][xi][ci] ; xi = x+1
    __shared__ float s_part[8][64];

    const int tid = threadIdx.x;
    const int l = tid & 63, w = tid >> 6;
    const int wco = w >> 2, wy = (w >> 1) & 1, wxh = w & 1;
    const int lg = l >> 4, l15 = l & 15;
    const int yp = blockIdx.x, n = blockIdx.z;
    const int y0 = yp * 2;

    const f32x4 fz = {0.f, 0.f, 0.f, 0.f};
    f32x4 acc[4][4];
#pragma unroll
    for (int m = 0; m < 4; ++m)
#pragma unroll
        for (int nf = 0; nf < 4; ++nf) acc[m][nf] = fz;

    const bf16x8* wv = reinterpret_cast<const bf16x8*>(wl);
    char* sb0 = (char*)&sB[0][0][0];
    const uint4 z4 = {0u, 0u, 0u, 0u};

    for (int ck = 0; ck < 4; ++ck) {
        __syncthreads();
        // ---- stage B chunk: rows y0-1 .. y0+2, ci chunk ck ----
        {
            const int r = w >> 1, xh = w & 1;
            const int ygl = y0 - 1 + r;
            if (ygl < 0 || ygl >= HH) {
                int t2 = xh * 64 + l;
                for (int i = t2; i < 528; i += 128)
                    *reinterpret_cast<uint4*>(sb0 + r * 8448 + i * 16) = z4;
            } else {
                if (xh == 0 && l < 8) {        // zero pad cols xi=0, xi=129
                    int col = (l < 4) ? 0 : 129, q = l & 3;
                    *reinterpret_cast<uint4*>(sb0 + r * 8448 + col * 64 + q * 16) = z4;
                }
                size_t rowbase = (((size_t)(n * HH + ygl)) * 4 + ck) * 8192;
#pragma unroll
                for (int i = 0; i < 4; ++i) {
                    const char* g = (const char*)inb + rowbase + xh * 4096 + i * 1024 + l * 16;
                    glds16(g, sb0 + r * 8448 + (1 + xh * 64 + i * 16) * 64);
                }
            }
        }
        __syncthreads();

        // ---- compute: 9 shifted GEMMs over this ci chunk ----
        bf16x8 a_cur[4];
#pragma unroll
        for (int m = 0; m < 4; ++m)
            a_cur[m] = wv[(((size_t)0 * 4 + ck) * 8 + wco * 4 + m) * 64 + l];

#pragma unroll
        for (int kk = 0; kk < 9; ++kk) {
            const int ky = kk / 3, kx = kk % 3;
            bf16x8 a_nxt[4];
            if (kk < 8) {
#pragma unroll
                for (int m = 0; m < 4; ++m)
                    a_nxt[m] = wv[((((size_t)kk + 1) * 4 + ck) * 8 + wco * 4 + m) * 64 + l];
            }
            const int rrow = wy + ky;
            bf16x8 b[4];
#pragma unroll
            for (int nf = 0; nf < 4; ++nf) {
                int xi = wxh * 64 + nf * 16 + l15 + kx;
                b[nf] = *reinterpret_cast<const bf16x8*>(
                    sb0 + rrow * 8448 + xi * 64 + lg * 16);
            }
#pragma unroll
            for (int nf = 0; nf < 4; ++nf)
#pragma unroll
                for (int m = 0; m < 4; ++m)
                    acc[m][nf] = __builtin_amdgcn_mfma_f32_16x16x32_bf16(
                        a_cur[m], b[nf], acc[m][nf], 0, 0, 0);
            if (kk < 8) {
#pragma unroll
                for (int m = 0; m < 4; ++m) a_cur[m] = a_nxt[m];
            }
        }
    }

    // ---- epilogue ----
    const int ybase = y0 + wy;
    if (CONV == 1) {
        const float a1 = *prelu_a;
#pragma unroll
        for (int m = 0; m < 4; ++m) {
            const int co0 = wco * 64 + m * 16 + lg * 4;
            const int ck_out = wco * 2 + (m >> 1);
            const int cin = (m & 1) * 16 + lg * 4;
#pragma unroll
            for (int nf = 0; nf < 4; ++nf) {
                const int xc = wxh * 64 + nf * 16 + l15;
                union { unsigned short u[4]; uint2 v; } pk;
#pragma unroll
                for (int jj = 0; jj < 4; ++jj) {
                    float f = acc[m][nf][jj] + bias[co0 + jj];
                    f = (f >= 0.f) ? f : a1 * f;
                    pk.u[jj] = f2bf(f);
                }
                *reinterpret_cast<uint2*>(outb +
                    (((size_t)(n * HH + ybase)) * 4 + ck_out) * 4096 + xc * 32 + cin) = pk.v;
            }
        }
    } else {
        float ps[4][4];
#pragma unroll
        for (int m = 0; m < 4; ++m)
#pragma unroll
            for (int jj = 0; jj < 4; ++jj) ps[m][jj] = 0.f;
#pragma unroll
        for (int m = 0; m < 4; ++m) {
            const int co0 = wco * 64 + m * 16 + lg * 4;
#pragma unroll
            for (int nf = 0; nf < 4; ++nf) {
                const int xc = wxh * 64 + nf * 16 + l15;
#pragma unroll
                for (int jj = 0; jj < 4; ++jj) {
                    float f = acc[m][nf][jj] + bias[co0 + jj];
                    outf[(((size_t)(n * C_ + co0 + jj)) * HH + ybase) * WW + xc] = f;
                    ps[m][jj] += f;
                }
            }
        }
#pragma unroll
        for (int m = 0; m < 4; ++m)
#pragma unroll
            for (int jj = 0; jj < 4; ++jj) {
                float s = ps[m][jj];
                s += __shfl_xor(s, 1); s += __shfl_xor(s, 2);
                s += __shfl_xor(s, 4); s += __shfl_xor(s, 8);
                ps[m][jj] = s;
            }
        if (l15 == 0) {
#pragma unroll
            for (int m = 0; m < 4; ++m)
#pragma unroll
                for (int jj = 0; jj < 4; ++jj)
                    s_part[w][m * 16 + lg * 4 + jj] = ps[m][jj];
        }
        __syncthreads();
        if (tid < C_) {
            const int half = tid >> 6;
            float s = 0.f;
#pragma unroll
            for (int w2 = 0; w2 < 4; ++w2) s += s_part[half * 4 + w2][tid & 63];
            partial[((size_t)(n * C_ + tid)) * NTILES + yp] = s;
        }
    }
}

// ---------------------------------------------------------------------------
// One block per sample: reduce partials -> x1, expert MLP, sigmoid gate.
__global__ __launch_bounds__(C_) void adapter_k(
    const float* __restrict__ partial, const int* __restrict__ intensity,
    const float* __restrict__ aW1, const float* __restrict__ ab1,
    const float* __restrict__ aW2, const float* __restrict__ ab2,
    float* __restrict__ sig)
{
    __shared__ float sx[C_];
    __shared__ float sa[CHID];
    const int n = blockIdx.x, c = threadIdx.x;

    float s = 0.f;
    for (int t = 0; t < NTILES; ++t)
        s += partial[(size_t)(n * C_ + c) * NTILES + t];
    sx[c] = s * (1.f / (float)(HH * WW));
    __syncthreads();

    const int idx = intensity[n] - 1;
    if (c < CHID) {
        float a = ab1[idx * CHID + c];
        const float* wrow = aW1 + (size_t)(idx * CHID + c) * C_;
        for (int k = 0; k < C_; ++k) a = fmaf(wrow[k], sx[k], a);
        sa[c] = fmaxf(a, 0.f);
    }
    __syncthreads();

    float g = ab2[idx * C_ + c];
    const float* w2row = aW2 + (size_t)(idx * C_ + c) * CHID;
#pragma unroll
    for (int k = 0; k < CHID; ++k) g = fmaf(w2row[k], sa[k], g);
    sig[n * C_ + c] = 1.f / (1.f + expf(-g));
}

// ---------------------------------------------------------------------------
// out = prelu(h * sig[n,c] + x, p2), in-place on d_out.
__global__ __launch_bounds__(256) void epilogue_k(
    const float* __restrict__ x, const float* __restrict__ sig,
    const float* __restrict__ prelu_a, float* __restrict__ out, int total4)
{
    const float a = *prelu_a;
    const int stride = gridDim.x * blockDim.x;
    for (int i = blockIdx.x * blockDim.x + threadIdx.x; i < total4; i += stride) {
        const int nc = (i * 4) >> 14;
        const float s = sig[nc];
        float4 h4 = ((const float4*)out)[i];
        float4 x4 = ((const float4*)x)[i];
        float4 v;
        v.x = h4.x * s + x4.x;  v.x = (v.x >= 0.f) ? v.x : a * v.x;
        v.y = h4.y * s + x4.y;  v.y = (v.y >= 0.f) ? v.y : a * v.y;
        v.z = h4.z * s + x4.z;  v.z = (v.z >= 0.f) ? v.z : a * v.z;
        v.w = h4.w * s + x4.w;  v.w = (v.w >= 0.f) ? v.w : a * v.w;
        ((float4*)out)[i] = v;
    }
}

// ---------------------------------------------------------------------------
extern "C" void kernel_launch(void* const* d_in, const int* in_sizes, int n_in,
                              void* d_out, int out_size, void* d_ws, size_t ws_size,
                              hipStream_t stream)
{
    const float* x         = (const float*)d_in[0];
    const int*   intensity = (const int*)  d_in[1];
    const float* w1        = (const float*)d_in[2];
    const float* b1        = (const float*)d_in[3];
    const float* p1        = (const float*)d_in[4];
    const float* w2        = (const float*)d_in[5];
    const float* b2        = (const float*)d_in[6];
    const float* aW1       = (const float*)d_in[7];
    const float* ab1       = (const float*)d_in[8];
    const float* aW2       = (const float*)d_in[9];
    const float* ab2       = (const float*)d_in[10];
    const float* p2        = (const float*)d_in[11];
    float* out = (float*)d_out;

    // xb (bf16 chunked-NHWC of x) borrows the front half of d_out: it is dead
    // before conv2 overwrites d_out with h.
    unsigned short* xb = (unsigned short*)d_out;              // 67.1 MB

    // workspace: h1b (bf16) | wl (packed weights) | partial | sig
    unsigned short* h1b = (unsigned short*)d_ws;              // 67.1 MB
    unsigned short* wl  = (unsigned short*)((char*)d_ws + (size_t)33554432 * 2);
    float* partial = (float*)((char*)wl + (size_t)294912 * 2);
    float* sig     = partial + (size_t)NN * C_ * NTILES;

    pack_w_k<<<dim3(576), dim3(64), 0, stream>>>(w1, w2, wl);
    to_cnhwc_k<<<dim3(HH, NN), dim3(256), 0, stream>>>(x, xb);

    conv_mfma_k<1><<<dim3(NTILES, 1, NN), dim3(512), 0, stream>>>(
        xb, wl, b1, p1, h1b, nullptr, nullptr);
    conv_mfma_k<2><<<dim3(NTILES, 1, NN), dim3(512), 0, stream>>>(
        h1b, wl + (size_t)147456, b2, nullptr, nullptr, out, partial);

    adapter_k<<<dim3(NN), dim3(C_), 0, stream>>>(
        partial, intensity, aW1, ab1, aW2, ab2, sig);

    const int total4 = NN * C_ * HH * WW / 4;
    epilogue_k<<<dim3(2048), dim3(256), 0, stream>>>(x, sig, p2, out, total4);
}

// Round 3
// 275.276 us; speedup vs baseline: 12.2573x; 1.0796x over previous
//
#include <hip/hip_runtime.h>
#include <hip/hip_bf16.h>
#include <math.h>

#define NN   16
#define C_   128
#define HH   128
#define WW   128
#define CHID 32
#define NTILES 64   // one tile per output y-pair

typedef short bf16x8 __attribute__((ext_vector_type(8)));
typedef float f32x4  __attribute__((ext_vector_type(4)));

__device__ inline void glds16(const void* g, void* l) {
    __builtin_amdgcn_global_load_lds(
        (const __attribute__((address_space(1))) unsigned int*)g,
        (__attribute__((address_space(3))) unsigned int*)l, 16, 0, 0);
}

__device__ inline unsigned short f2bf(float f) {
    __hip_bfloat16 h = __float2bfloat16(f);
    return *reinterpret_cast<unsigned short*>(&h);
}

// ---------------------------------------------------------------------------
// Pack conv weights into MFMA-A fragment-linear layout (bf16):
// wl[conv][kk 9][ck 4][cot 8][lane 64][8] ; value = W[co][ci][ky][kx]
// with co = cot*16 + (l&15), ci = ck*32 + (l>>4)*8 + j, kk = ky*3+kx.
__global__ __launch_bounds__(64) void pack_w_k(
    const float* __restrict__ w1, const float* __restrict__ w2,
    unsigned short* __restrict__ wl)
{
    const int b = blockIdx.x;                 // conv*288 + kk*32 + ck*8 + cot
    const int conv = b / 288, rem = b % 288;
    const int kk = rem / 32, ck = (rem % 32) / 8, cot = rem % 8;
    const int l = threadIdx.x;
    const int co  = cot * 16 + (l & 15);
    const int ci0 = ck * 32 + (l >> 4) * 8;
    const float* W = conv ? w2 : w1;
    union { unsigned short u[8]; uint4 v; } pk;
#pragma unroll
    for (int j = 0; j < 8; ++j)
        pk.u[j] = f2bf(W[(size_t)(co * C_ + ci0 + j) * 9 + kk]);
    unsigned short* dst = wl + (size_t)conv * 147456 +
        ((((size_t)kk * 4 + ck) * 8 + cot) * 64 + l) * 8;
    *reinterpret_cast<uint4*>(dst) = pk.v;
}

// ---------------------------------------------------------------------------
// fp32 NCHW -> bf16 chunked-NHWC: xb[n][y][ck4][x128][ci32]
// LDS tile swizzled: row x holds ci-octet s at slot s ^ h(x), h(x)=(x>>2)&7.
__global__ __launch_bounds__(256) void to_cnhwc_k(
    const float* __restrict__ x, unsigned short* __restrict__ xb)
{
    __shared__ unsigned short s_t[128][136];   // row 272B = 17 x 16B slots
    const int y = blockIdx.x, n = blockIdx.y, t = threadIdx.x;

#pragma unroll
    for (int p = 0; p < 16; ++p) {
        int fi = p * 256 + t;                  // float4 index over [ci][x/4]
        int ci = fi >> 5, x0 = (fi & 31) * 4;
        float4 v = *reinterpret_cast<const float4*>(
            x + (((size_t)(n * C_ + ci) * HH) + y) * WW + x0);
        const int slot = ((ci >> 3) ^ ((x0 >> 2) & 7)) * 8 + (ci & 7);
        s_t[x0 + 0][slot] = f2bf(v.x);
        s_t[x0 + 1][slot] = f2bf(v.y);
        s_t[x0 + 2][slot] = f2bf(v.z);
        s_t[x0 + 3][slot] = f2bf(v.w);
    }
    __syncthreads();
    unsigned short* dstbase = xb + ((size_t)(n * HH + y)) * 16384;
#pragma unroll
    for (int p = 0; p < 8; ++p) {
        int o = p * 256 + t;                   // 16B unit: 2048 total
        int ck = o >> 9, u = o & 511;
        int xc = u >> 2, q = u & 3;
        int k = ck * 4 + q;                    // ci-octet pair index (16B)
        uint4 v = *reinterpret_cast<const uint4*>(
            &s_t[xc][(k ^ ((xc >> 2) & 7)) * 8]);
        *reinterpret_cast<uint4*>(dstbase + (size_t)ck * 4096 + xc * 32 + q * 8) = v;
    }
}

// ---------------------------------------------------------------------------
// Implicit-GEMM 3x3 conv. Block: 128 c_out x (2 rows x 128 x) at (n, yp).
// 8 waves: w -> wco = w>>2, wy = (w>>1)&1, wxh = w&1 ; wave tile 64co x 64x.
// B tile in LDS is slot-swizzled: row xi's 16B slot s holds ci-sub s ^ f(xi),
// f(xi) = (xi>>1)&3  -> ds_read_b128 spreads over all 8 bank-quads.
// CONV==1: out bf16 chunked-NHWC + PReLU (LDS-repacked 16B stores).
// CONV==2: out fp32 NCHW + avg-pool partials.
template<int CONV>
__global__ __launch_bounds__(512) void conv_mfma_k(
    const unsigned short* __restrict__ inb,   // bf16 chunked-NHWC
    const unsigned short* __restrict__ wl,    // this conv's packed frags
    const float* __restrict__ bias,
    const float* __restrict__ prelu_a,
    unsigned short* __restrict__ outb,        // CONV==1
    float* __restrict__ outf,                 // CONV==2
    float* __restrict__ partial)              // CONV==2
{
    __shared__ char  smem[34816];             // B tile (33792) / repack (34816)
    __shared__ float s_part[8][64];

    const int tid = threadIdx.x;
    const int l = tid & 63, w = tid >> 6;
    const int wco = w >> 2, wy = (w >> 1) & 1, wxh = w & 1;
    const int lg = l >> 4, l15 = l & 15;
    const int yp = blockIdx.x, n = blockIdx.z;
    const int y0 = yp * 2;

    const f32x4 fz = {0.f, 0.f, 0.f, 0.f};
    f32x4 acc[4][4];
#pragma unroll
    for (int m = 0; m < 4; ++m)
#pragma unroll
        for (int nf = 0; nf < 4; ++nf) acc[m][nf] = fz;

    const bf16x8* wv = reinterpret_cast<const bf16x8*>(wl);
    char* sb0 = smem;
    const uint4 z4 = {0u, 0u, 0u, 0u};

    for (int ck = 0; ck < 4; ++ck) {
        __syncthreads();
        // ---- stage B chunk: rows y0-1 .. y0+2, ci chunk ck ----
        {
            const int r = w >> 1, xh = w & 1;
            const int ygl = y0 - 1 + r;
            if (ygl < 0 || ygl >= HH) {
                int t2 = xh * 64 + l;
                for (int i = t2; i < 528; i += 128)
                    *reinterpret_cast<uint4*>(sb0 + r * 8448 + i * 16) = z4;
            } else {
                if (xh == 0 && l < 8) {        // zero pad cols xi=0, xi=129
                    int col = (l < 4) ? 0 : 129, q = l & 3;
                    *reinterpret_cast<uint4*>(sb0 + r * 8448 + col * 64 + q * 16) = z4;
                }
                size_t rowbase = (((size_t)(n * HH + ygl)) * 4 + ck) * 8192;
#pragma unroll
                for (int i = 0; i < 4; ++i) {
                    // lane l -> pixel p, LDS slot (l&3); pre-swizzle the SOURCE
                    // so that slot s_l holds ci-sub s_l ^ f(1+p).
                    const int p  = xh * 64 + i * 16 + (l >> 2);
                    const int sd = (l & 3) ^ (((1 + p) >> 1) & 3);
                    const char* g = (const char*)inb + rowbase + (size_t)p * 64 + sd * 16;
                    glds16(g, sb0 + r * 8448 + (1 + xh * 64 + i * 16) * 64);
                }
            }
        }
        __syncthreads();

        // ---- compute: 9 shifted GEMMs over this ci chunk ----
        bf16x8 a_cur[4];
#pragma unroll
        for (int m = 0; m < 4; ++m)
            a_cur[m] = wv[(((size_t)0 * 4 + ck) * 8 + wco * 4 + m) * 64 + l];

#pragma unroll
        for (int kk = 0; kk < 9; ++kk) {
            const int ky = kk / 3, kx = kk % 3;
            bf16x8 a_nxt[4];
            if (kk < 8) {
#pragma unroll
                for (int m = 0; m < 4; ++m)
                    a_nxt[m] = wv[((((size_t)kk + 1) * 4 + ck) * 8 + wco * 4 + m) * 64 + l];
            }
            const int rrow = wy + ky;
            bf16x8 b[4];
#pragma unroll
            for (int nf = 0; nf < 4; ++nf) {
                int xi = wxh * 64 + nf * 16 + l15 + kx;
                int slot = lg ^ ((xi >> 1) & 3);
                b[nf] = *reinterpret_cast<const bf16x8*>(
                    sb0 + rrow * 8448 + xi * 64 + slot * 16);
            }
#pragma unroll
            for (int nf = 0; nf < 4; ++nf)
#pragma unroll
                for (int m = 0; m < 4; ++m)
                    acc[m][nf] = __builtin_amdgcn_mfma_f32_16x16x32_bf16(
                        a_cur[m], b[nf], acc[m][nf], 0, 0, 0);
            if (kk < 8) {
#pragma unroll
                for (int m = 0; m < 4; ++m) a_cur[m] = a_nxt[m];
            }
        }
    }

    // ---- epilogue ----
    const int ybase = y0 + wy;
    if (CONV == 1) {
        const float a1 = *prelu_a;
        unsigned short (*s_rp)[136] = reinterpret_cast<unsigned short (*)[136]>(smem);
        // Repack via LDS so each global store is a full 16B line segment.
        for (int r = 0; r < 2; ++r) {
            __syncthreads();
            if (wy == r) {
#pragma unroll
                for (int m = 0; m < 4; ++m) {
                    const int co0 = wco * 64 + m * 16 + lg * 4;
#pragma unroll
                    for (int nf = 0; nf < 4; ++nf) {
                        const int xc = wxh * 64 + nf * 16 + l15;
                        union { unsigned short u[4]; uint2 v; } pk;
#pragma unroll
                        for (int jj = 0; jj < 4; ++jj) {
                            float f = acc[m][nf][jj] + bias[co0 + jj];
                            f = (f >= 0.f) ? f : a1 * f;
                            pk.u[jj] = f2bf(f);
                        }
                        *reinterpret_cast<uint2*>(&s_rp[xc][co0]) = pk.v;
                    }
                }
            }
            __syncthreads();
            const int y = y0 + r;
#pragma unroll
            for (int p = 0; p < 4; ++p) {
                int u = p * 512 + tid;         // 2048 16B units: [xc][k]
                int xc = u >> 4, k = u & 15;
                uint4 v = *reinterpret_cast<const uint4*>(&s_rp[xc][k * 8]);
                *reinterpret_cast<uint4*>(outb +
                    (((size_t)(n * HH + y)) * 4 + (k >> 2)) * 4096 +
                    xc * 32 + (k & 3) * 8) = v;
            }
        }
    } else {
        float ps[4][4];
#pragma unroll
        for (int m = 0; m < 4; ++m)
#pragma unroll
            for (int jj = 0; jj < 4; ++jj) ps[m][jj] = 0.f;
#pragma unroll
        for (int m = 0; m < 4; ++m) {
            const int co0 = wco * 64 + m * 16 + lg * 4;
#pragma unroll
            for (int nf = 0; nf < 4; ++nf) {
                const int xc = wxh * 64 + nf * 16 + l15;
#pragma unroll
                for (int jj = 0; jj < 4; ++jj) {
                    float f = acc[m][nf][jj] + bias[co0 + jj];
                    outf[(((size_t)(n * C_ + co0 + jj)) * HH + ybase) * WW + xc] = f;
                    ps[m][jj] += f;
                }
            }
        }
#pragma unroll
        for (int m = 0; m < 4; ++m)
#pragma unroll
            for (int jj = 0; jj < 4; ++jj) {
                float s = ps[m][jj];
                s += __shfl_xor(s, 1); s += __shfl_xor(s, 2);
                s += __shfl_xor(s, 4); s += __shfl_xor(s, 8);
                ps[m][jj] = s;
            }
        if (l15 == 0) {
#pragma unroll
            for (int m = 0; m < 4; ++m)
#pragma unroll
                for (int jj = 0; jj < 4; ++jj)
                    s_part[w][m * 16 + lg * 4 + jj] = ps[m][jj];
        }
        __syncthreads();
        if (tid < C_) {
            const int half = tid >> 6;
            float s = 0.f;
#pragma unroll
            for (int w2 = 0; w2 < 4; ++w2) s += s_part[half * 4 + w2][tid & 63];
            partial[((size_t)(n * C_ + tid)) * NTILES + yp] = s;
        }
    }
}

// ---------------------------------------------------------------------------
// One block per sample: reduce partials -> x1, expert MLP, sigmoid gate.
__global__ __launch_bounds__(C_) void adapter_k(
    const float* __restrict__ partial, const int* __restrict__ intensity,
    const float* __restrict__ aW1, const float* __restrict__ ab1,
    const float* __restrict__ aW2, const float* __restrict__ ab2,
    float* __restrict__ sig)
{
    __shared__ float sx[C_];
    __shared__ float sa[CHID];
    const int n = blockIdx.x, c = threadIdx.x;

    float s = 0.f;
    for (int t = 0; t < NTILES; ++t)
        s += partial[(size_t)(n * C_ + c) * NTILES + t];
    sx[c] = s * (1.f / (float)(HH * WW));
    __syncthreads();

    const int idx = intensity[n] - 1;
    if (c < CHID) {
        float a = ab1[idx * CHID + c];
        const float* wrow = aW1 + (size_t)(idx * CHID + c) * C_;
        for (int k = 0; k < C_; ++k) a = fmaf(wrow[k], sx[k], a);
        sa[c] = fmaxf(a, 0.f);
    }
    __syncthreads();

    float g = ab2[idx * C_ + c];
    const float* w2row = aW2 + (size_t)(idx * C_ + c) * CHID;
#pragma unroll
    for (int k = 0; k < CHID; ++k) g = fmaf(w2row[k], sa[k], g);
    sig[n * C_ + c] = 1.f / (1.f + expf(-g));
}

// ---------------------------------------------------------------------------
// out = prelu(h * sig[n,c] + x, p2), in-place on d_out.
__global__ __launch_bounds__(256) void epilogue_k(
    const float* __restrict__ x, const float* __restrict__ sig,
    const float* __restrict__ prelu_a, float* __restrict__ out, int total4)
{
    const float a = *prelu_a;
    const int stride = gridDim.x * blockDim.x;
    for (int i = blockIdx.x * blockDim.x + threadIdx.x; i < total4; i += stride) {
        const int nc = (i * 4) >> 14;
        const float s = sig[nc];
        float4 h4 = ((const float4*)out)[i];
        float4 x4 = ((const float4*)x)[i];
        float4 v;
        v.x = h4.x * s + x4.x;  v.x = (v.x >= 0.f) ? v.x : a * v.x;
        v.y = h4.y * s + x4.y;  v.y = (v.y >= 0.f) ? v.y : a * v.y;
        v.z = h4.z * s + x4.z;  v.z = (v.z >= 0.f) ? v.z : a * v.z;
        v.w = h4.w * s + x4.w;  v.w = (v.w >= 0.f) ? v.w : a * v.w;
        ((float4*)out)[i] = v;
    }
}

// ---------------------------------------------------------------------------
extern "C" void kernel_launch(void* const* d_in, const int* in_sizes, int n_in,
                              void* d_out, int out_size, void* d_ws, size_t ws_size,
                              hipStream_t stream)
{
    const float* x         = (const float*)d_in[0];
    const int*   intensity = (const int*)  d_in[1];
    const float* w1        = (const float*)d_in[2];
    const float* b1        = (const float*)d_in[3];
    const float* p1        = (const float*)d_in[4];
    const float* w2        = (const float*)d_in[5];
    const float* b2        = (const float*)d_in[6];
    const float* aW1       = (const float*)d_in[7];
    const float* ab1       = (const float*)d_in[8];
    const float* aW2       = (const float*)d_in[9];
    const float* ab2       = (const float*)d_in[10];
    const float* p2        = (const float*)d_in[11];
    float* out = (float*)d_out;

    // xb (bf16 chunked-NHWC of x) borrows the front half of d_out: it is dead
    // before conv2 overwrites d_out with h.
    unsigned short* xb = (unsigned short*)d_out;              // 67.1 MB

    // workspace: h1b (bf16) | wl (packed weights) | partial | sig
    unsigned short* h1b = (unsigned short*)d_ws;              // 67.1 MB
    unsigned short* wl  = (unsigned short*)((char*)d_ws + (size_t)33554432 * 2);
    float* partial = (float*)((char*)wl + (size_t)294912 * 2);
    float* sig     = partial + (size_t)NN * C_ * NTILES;

    pack_w_k<<<dim3(576), dim3(64), 0, stream>>>(w1, w2, wl);
    to_cnhwc_k<<<dim3(HH, NN), dim3(256), 0, stream>>>(x, xb);

    conv_mfma_k<1><<<dim3(NTILES, 1, NN), dim3(512), 0, stream>>>(
        xb, wl, b1, p1, h1b, nullptr, nullptr);
    conv_mfma_k<2><<<dim3(NTILES, 1, NN), dim3(512), 0, stream>>>(
        h1b, wl + (size_t)147456, b2, nullptr, nullptr, out, partial);

    adapter_k<<<dim3(NN), dim3(C_), 0, stream>>>(
        partial, intensity, aW1, ab1, aW2, ab2, sig);

    const int total4 = NN * C_ * HH * WW / 4;
    epilogue_k<<<dim3(2048), dim3(256), 0, stream>>>(x, sig, p2, out, total4);
}